// Round 9
// baseline (295.401 us; speedup 1.0000x reference)
//
#include <hip/hip_runtime.h>
#include <float.h>
#include <limits.h>

#define N_Q 8192
#define M_PTS 50000
#define DIM 128
#define KNN 10
#define NCLS 10
#define NCHUNK 16          // 16 chunks: c<5 -> 196 tiles, else 195 (3125 total)
#define CPC 8              // candidates kept per (query, chunk)
#define NCAND (NCHUNK*CPC) // 128 candidates per query
#define NSEL 16            // exact-rescored candidates per query
#define TPL 4              // per-lane-class top depth
#define QPB 128            // queries per block (4 waves x 32)
#define XN4 (N_Q*DIM/4)    // 262144 float4 in x
#define YN4 (M_PTS*DIM/4)  // 1600000 float4 in y

typedef __attribute__((ext_vector_type(8))) short bf16x8;
typedef __attribute__((ext_vector_type(4))) float f32x4;
typedef unsigned int u32;
typedef unsigned short u16;

__device__ __forceinline__ int chunk_t0(int c) { return c * 195 + (c < 5 ? c : 5); }

__device__ __forceinline__ u16 rne_bf16(float f) {
    u32 u = __float_as_uint(f);
    u32 r = u + 0x7FFFu + ((u >> 16) & 1u);
    return (u16)(r >> 16);
}

// ---------------------------------------------------------------------------
// Prep: xb = bf16(-2x) row-major (A-frags); yt = bf16(y) pre-swizzled into
// MFMA B-fragment tile records (4 KB/tile; lane l reads its bf16x8 for
// k-block b at T*4096 + b*1024 + l*16); y2 = ||y_j||^2 fp32.
// ---------------------------------------------------------------------------
__global__ __launch_bounds__(256) void prep_kernel(
    const float4* __restrict__ x4, const float4* __restrict__ y4,
    ushort4* __restrict__ xb4, u16* __restrict__ yt,
    float* __restrict__ y2) {
    int t = blockIdx.x * 256 + threadIdx.x;
    if (t < XN4) {
        float4 v = x4[t];
        ushort4 o;
        o.x = rne_bf16(-2.0f * v.x); o.y = rne_bf16(-2.0f * v.y);
        o.z = rne_bf16(-2.0f * v.z); o.w = rne_bf16(-2.0f * v.w);
        xb4[t] = o;
    } else {
        int j = t - XN4;            // float4 index into y
        int row = j >> 5;           // point 0..49999
        int d4  = j & 31;           // which float4 of the row
        float4 v = y4[j];
        ushort4 o;
        o.x = rne_bf16(v.x); o.y = rne_bf16(v.y);
        o.z = rne_bf16(v.z); o.w = rne_bf16(v.w);
        int T = row >> 4, nr = row & 15;
        int b = d4 >> 3, g = (d4 >> 1) & 3, h = d4 & 1;
        size_t dst = (size_t)T * 2048 + b * 512 + (g * 16 + nr) * 8 + h * 4; // u16 units
        *(ushort4*)(yt + dst) = o;
        float p = v.x * v.x + v.y * v.y + v.z * v.z + v.w * v.w;
        #pragma unroll
        for (int off = 16; off > 0; off >>= 1) p += __shfl_xor(p, off, 64);
        if ((j & 31) == 0) y2[row] = p;
    }
}

// ---------------------------------------------------------------------------
// Filter: no LDS, no barriers in the K-loop (round-8 structure). NEW: the two
// serial 4-deep MFMA accumulation chains are split into FOUR independent
// 2-deep chains (heads consume a persistent zero quad as C, so there is no
// per-tile accumulator zeroing either). Extract pays +1 pair-sum add per
// score; per-tile MFMA critical path halves. Per score: 2 add + bfi + min +
// 3 med3. LDS only for the final per-query merge.
// ---------------------------------------------------------------------------
__global__ __launch_bounds__(256, 4) void knn_filter(
    const u16* __restrict__ xb, const u16* __restrict__ yt,
    const float* __restrict__ y2, u32* __restrict__ ckey) {
    const int lane = threadIdx.x & 63;
    const int wid  = threadIdx.x >> 6;      // wave 0..3
    const int g    = lane >> 4;             // k-group 0..3
    const int nrow = lane & 15;             // point-in-tile (B col / C col)
    const int chunk = blockIdx.x;           // gridDim.x=16 -> XCD = chunk%8
    const int qb    = blockIdx.y;
    const int t0 = chunk_t0(chunk);
    const int tn = 195 + (chunk < 5 ? 1 : 0);
    const int p0 = t0 * 16;
    const int qw = qb * QPB + wid * 32;

    // A fragments: 2 query-sets x 4 k-blocks (k = 32*b + 8*g + e), 32 VGPRs
    bf16x8 a[2][4];
    #pragma unroll
    for (int s = 0; s < 2; ++s) {
        const u16* xr = xb + (size_t)(qw + s * 16 + nrow) * DIM + g * 8;
        #pragma unroll
        for (int b = 0; b < 4; ++b) a[s][b] = *(const bf16x8*)(xr + b * 32);
    }

    float ts[8][TPL];
    #pragma unroll
    for (int r = 0; r < 8; ++r)
        #pragma unroll
        for (int l = 0; l < TPL; ++l) ts[r][l] = FLT_MAX;

    const f32x4 Z = {0.f, 0.f, 0.f, 0.f};   // persistent zero C-quad

    const u16* ytp = yt + (size_t)t0 * 2048 + lane * 8;   // per-lane record ptr
    const float* y2p = y2 + p0 + nrow;

    u32 rel = (u32)nrow;
    for (int t = 0; t < tn; ++t) {
        const u16* rec = ytp + (size_t)t * 2048;
        bf16x8 b0 = *(const bf16x8*)(rec);
        bf16x8 b1 = *(const bf16x8*)(rec + 512);
        bf16x8 b2 = *(const bf16x8*)(rec + 1024);
        bf16x8 b3 = *(const bf16x8*)(rec + 1536);
        float y2n = y2p[t * 16];
        // 4 independent chain heads, then 4 independent chain tails
        f32x4 c0a = __builtin_amdgcn_mfma_f32_16x16x32_bf16(a[0][0], b0, Z, 0, 0, 0);
        f32x4 c0b = __builtin_amdgcn_mfma_f32_16x16x32_bf16(a[0][2], b2, Z, 0, 0, 0);
        f32x4 c1a = __builtin_amdgcn_mfma_f32_16x16x32_bf16(a[1][0], b0, Z, 0, 0, 0);
        f32x4 c1b = __builtin_amdgcn_mfma_f32_16x16x32_bf16(a[1][2], b2, Z, 0, 0, 0);
        c0a = __builtin_amdgcn_mfma_f32_16x16x32_bf16(a[0][1], b1, c0a, 0, 0, 0);
        c0b = __builtin_amdgcn_mfma_f32_16x16x32_bf16(a[0][3], b3, c0b, 0, 0, 0);
        c1a = __builtin_amdgcn_mfma_f32_16x16x32_bf16(a[1][1], b1, c1a, 0, 0, 0);
        c1b = __builtin_amdgcn_mfma_f32_16x16x32_bf16(a[1][3], b3, c1b, 0, 0, 0);
        #pragma unroll
        for (int i = 0; i < 4; ++i) {
            float sc = (c0a[i] + c0b[i]) + y2n;
            float key = __uint_as_float((__float_as_uint(sc) & 0xFFFFF000u) | rel);
            float o0 = ts[i][0], o1 = ts[i][1], o2 = ts[i][2];
            ts[i][0] = fminf(o0, key);
            ts[i][1] = __builtin_amdgcn_fmed3f(key, o0, o1);
            ts[i][2] = __builtin_amdgcn_fmed3f(key, o1, o2);
            ts[i][3] = __builtin_amdgcn_fmed3f(key, o2, ts[i][3]);
        }
        #pragma unroll
        for (int i = 0; i < 4; ++i) {
            float sc = (c1a[i] + c1b[i]) + y2n;
            float key = __uint_as_float((__float_as_uint(sc) & 0xFFFFF000u) | rel);
            float o0 = ts[4 + i][0], o1 = ts[4 + i][1], o2 = ts[4 + i][2];
            ts[4 + i][0] = fminf(o0, key);
            ts[4 + i][1] = __builtin_amdgcn_fmed3f(key, o0, o1);
            ts[4 + i][2] = __builtin_amdgcn_fmed3f(key, o1, o2);
            ts[4 + i][3] = __builtin_amdgcn_fmed3f(key, o2, ts[4 + i][3]);
        }
        rel += 16;
    }

    // ---- merge 16 lane-classes -> per-query sorted top-8 (LDS, 2 barriers) --
    __shared__ u32 smem[QPB * 65];          // 33280 B
    #pragma unroll
    for (int s = 0; s < 2; ++s)
        #pragma unroll
        for (int r = 0; r < 4; ++r) {
            int ql = wid * 32 + s * 16 + g * 4 + r;
            #pragma unroll
            for (int l = 0; l < TPL; ++l)
                smem[ql * 65 + nrow * TPL + l] = __float_as_uint(ts[s * 4 + r][l]);
        }
    __syncthreads();
    if (threadIdx.x < QPB) {
        int ql = threadIdx.x;
        float bs[CPC];
        #pragma unroll
        for (int i = 0; i < CPC; ++i) bs[i] = FLT_MAX;
        for (int e = 0; e < 16 * TPL; ++e) {      // stride-65: conflict-free
            float f = __uint_as_float(smem[ql * 65 + e]);
            #pragma unroll
            for (int q2 = 0; q2 < CPC; ++q2) {
                float mn = fminf(bs[q2], f);
                f = fmaxf(bs[q2], f);
                bs[q2] = mn;
            }
        }
        u32* dst = ckey + ((size_t)(qb * QPB + ql) * NCHUNK + chunk) * CPC;
        #pragma unroll
        for (int i = 0; i < CPC; ++i) dst[i] = __float_as_uint(bs[i]);
    }
}

// ---------------------------------------------------------------------------
// Finalize: 16 queries per block (4/wave). Select runs 4-way parallel per
// wave with sorted-chunk early-out; exact fp64 rescore one candidate per
// lane; vote on lanes 0-3. Ties: (score, idx) = jax top_k; class ties ->
// LARGEST label (reference reversed-argmax).
// ---------------------------------------------------------------------------
__global__ __launch_bounds__(256) void knn_finalize(
    const u32* __restrict__ ckey, const float* __restrict__ x,
    const float* __restrict__ y, const int* __restrict__ labels,
    int* __restrict__ out) {
    const int lane = threadIdx.x & 63;
    const int wid  = threadIdx.x >> 6;
    const int qbase = blockIdx.x * 16;

    __shared__ u32 skey[16][NCAND];
    __shared__ int sidx[16][NSEL];
    __shared__ double sex[16][NSEL];

    for (int i = threadIdx.x; i < 16 * NCAND; i += 256)
        skey[i >> 7][i & 127] = ckey[(size_t)(qbase + (i >> 7)) * NCAND + (i & 127)];
    __syncthreads();

    if (lane < 4) {                         // 4 parallel selects per wave
        int ql = wid * 4 + lane;
        float bs[NSEL]; int bi[NSEL];
        #pragma unroll
        for (int i = 0; i < NSEL; ++i) { bs[i] = FLT_MAX; bi[i] = 0; }
        for (int c = 0; c < NCHUNK; ++c) {
            int base = c * CPC;
            for (int j = 0; j < CPC; ++j) {
                u32 u = skey[ql][base + j];
                float f = __uint_as_float(u);
                if (f >= bs[NSEL - 1]) break;   // chunk sorted: rest can't qualify
                int id = chunk_t0(c) * 16 + (int)(u & 0xFFFu);
                #pragma unroll
                for (int pp = 0; pp < NSEL; ++pp) {
                    bool lt = f < bs[pp];
                    float nf = lt ? bs[pp] : f;  int nid = lt ? bi[pp] : id;
                    bs[pp] = lt ? f : bs[pp];    bi[pp] = lt ? id : bi[pp];
                    f = nf; id = nid;
                }
            }
        }
        #pragma unroll
        for (int i = 0; i < NSEL; ++i) sidx[ql][i] = bi[i];
    }
    __syncthreads();

    // exact fp64 rescore: lane -> (qloc = lane>>4, cand = lane&15)
    const int qloc = lane >> 4;
    const int cand = lane & 15;
    const int ql = wid * 4 + qloc;
    const int idx = sidx[ql][cand];
    const float4* xr = (const float4*)(x + (size_t)(qbase + ql) * DIM);
    const float4* yr = (const float4*)(y + (size_t)idx * DIM);
    double dy2 = 0.0, dxy = 0.0;
    #pragma unroll 8
    for (int i = 0; i < 32; ++i) {
        float4 yv = yr[i];
        float4 xv = xr[i];
        dy2 = fma((double)yv.x, (double)yv.x, dy2);
        dy2 = fma((double)yv.y, (double)yv.y, dy2);
        dy2 = fma((double)yv.z, (double)yv.z, dy2);
        dy2 = fma((double)yv.w, (double)yv.w, dy2);
        dxy = fma((double)xv.x, (double)yv.x, dxy);
        dxy = fma((double)xv.y, (double)yv.y, dxy);
        dxy = fma((double)xv.z, (double)yv.z, dxy);
        dxy = fma((double)xv.w, (double)yv.w, dxy);
    }
    sex[ql][cand] = dy2 - 2.0 * dxy;
    __syncthreads();

    if (lane < 4) {                         // 4 parallel votes per wave
        int ql2 = wid * 4 + lane;
        double tsv[KNN]; int ti[KNN];
        #pragma unroll
        for (int i = 0; i < KNN; ++i) { tsv[i] = 1e300; ti[i] = INT_MAX; }
        #pragma unroll
        for (int c = 0; c < NSEL; ++c) {
            double s = sex[ql2][c];
            int id = sidx[ql2][c];
            #pragma unroll
            for (int pp = 0; pp < KNN; ++pp) {
                bool lt = (s < tsv[pp]) || (s == tsv[pp] && id < ti[pp]);
                double ns = lt ? tsv[pp] : s;  int nid = lt ? ti[pp] : id;
                tsv[pp] = lt ? s : tsv[pp];    ti[pp] = lt ? id : ti[pp];
                s = ns; id = nid;
            }
        }
        int lab[KNN];
        #pragma unroll
        for (int i = 0; i < KNN; ++i) lab[i] = labels[ti[i]];
        int bestc = 0, bestn = -1;
        #pragma unroll
        for (int c = 0; c < NCLS; ++c) {
            int n = 0;
            #pragma unroll
            for (int i = 0; i < KNN; ++i) n += (lab[i] == c) ? 1 : 0;
            if (n >= bestn) { bestn = n; bestc = c; }   // >= : ties -> larger label
        }
        out[qbase + ql2] = bestc;
    }
}

// ---------------------------------------------------------------------------
extern "C" void kernel_launch(void* const* d_in, const int* in_sizes, int n_in,
                              void* d_out, int out_size, void* d_ws, size_t ws_size,
                              hipStream_t stream) {
    const float* x      = (const float*)d_in[0];
    const float* y      = (const float*)d_in[1];
    const int*   labels = (const int*)d_in[2];
    // d_in[3] is k == 10, baked in.

    char* ws = (char*)d_ws;
    size_t off = 0;
    u16* xb = (u16*)(ws + off);     off += (size_t)N_Q * DIM * 2;        //  2.10 MB
    u16* yt = (u16*)(ws + off);     off += (size_t)3125 * 4096;          // 12.80 MB (swizzled tiles)
    float* y2 = (float*)(ws + off); off += (size_t)M_PTS * 4 + 4096;     //  0.20 MB
    u32* ckey = (u32*)(ws + off);   off += (size_t)N_Q * NCAND * 4;      //  4.19 MB
    int* out = (int*)d_out;

    prep_kernel<<<(XN4 + YN4) / 256, 256, 0, stream>>>(
        (const float4*)x, (const float4*)y, (ushort4*)xb, yt, y2);
    knn_filter<<<dim3(NCHUNK, N_Q / QPB), 256, 0, stream>>>(xb, yt, y2, ckey);
    knn_finalize<<<N_Q / 16, 256, 0, stream>>>(ckey, x, y, labels, out);
}